// Round 11
// baseline (1717.476 us; speedup 1.0000x reference)
//
#include <hip/hip_runtime.h>

// Problem sizes (fixed)
#define BB 512
#define TT 256
#define II 256
#define HH 512
// K = II + HH = 768 ; 4H = 2048

typedef __attribute__((ext_vector_type(8))) short bf16x8;   // 4 VGPRs (8 bf16)
typedef __attribute__((ext_vector_type(4))) float f32x4;    // 16x16 accumulator

__device__ __forceinline__ unsigned short f2bf(float f) {
  union { float f; unsigned u; } v; v.f = f;
  unsigned r = v.u + 0x7fffu + ((v.u >> 16) & 1u);   // RNE
  return (unsigned short)(r >> 16);
}

// Poll a per-lane flag pointer until *p >= t across the wave (agent scope).
__device__ __forceinline__ void pollw(const int* p, int t) {
  int iter = 0;
  for (;;) {
    int v = __hip_atomic_load(p, __ATOMIC_RELAXED, __HIP_MEMORY_SCOPE_AGENT);
    if (__all(v >= t)) break;
    if (++iter >= (1 << 17)) break;
    __builtin_amdgcn_s_sleep(1);
  }
}

// -------- workspace layout (bytes) --------
// [0,4096)                : per-group member flags (32 groups x 128B; 8 ints used)
// [4096, 4096+2*524288)   : hswz double buffer: [kchunk 16][group 32][lane 64][16B]
// [OFF_XSWZ, +64MB)       : x in A-frag swizzle (bf16): [t][kc 8][rowchunk 32][lane][16B]
// [OFF_HIST, +16MB)       : 'a' buffer (fp32, [B*T][32]) — hist is GONE (fc1 fused)
#define OFF_CNT   0
#define OFF_HSWZ  4096
#define OFF_XSWZ  1052672ULL
#define OFF_HIST  68161536ULL
#define ZERO_WORDS 263168   // (4096 + 2*524288)/4

__global__ void zero_k(unsigned* __restrict__ p, int n) {
  int i = blockIdx.x * blockDim.x + threadIdx.x;
  if (i < n) p[i] = 0u;
}

// Swizzle x[b][t][k] (fp32) -> xswz[t][kc][rc][lane][8] (bf16), A-frag order.
__global__ __launch_bounds__(256) void prep_x(const float* __restrict__ x,
                                              unsigned char* __restrict__ ws) {
  __shared__ unsigned short xs[16][264];   // 16 rows x 256 k (+8 pad)
  const int t = blockIdx.x >> 5, rc = blockIdx.x & 31;
  const int tid = threadIdx.x;
  {
    const int r = tid >> 4, seg = tid & 15;
    const float* src = x + ((size_t)(rc * 16 + r) * TT + t) * II + seg * 16;
    const float4* s4 = (const float4*)src;
#pragma unroll
    for (int q = 0; q < 4; ++q) {
      float4 v = s4[q];
      xs[r][seg * 16 + q * 4 + 0] = f2bf(v.x);
      xs[r][seg * 16 + q * 4 + 1] = f2bf(v.y);
      xs[r][seg * 16 + q * 4 + 2] = f2bf(v.z);
      xs[r][seg * 16 + q * 4 + 3] = f2bf(v.w);
    }
  }
  __syncthreads();
  const int lane = tid & 63;
  const int row16 = lane & 15, koff = (lane >> 4) * 8;
#pragma unroll
  for (int kc = tid >> 6; kc < 8; kc += 4) {
    union { unsigned short h[8]; uint4 v; } pk;
#pragma unroll
    for (int j = 0; j < 8; ++j) pk.h[j] = xs[row16][kc * 32 + koff + j];
    *(uint4*)(ws + OFF_XSWZ + (size_t)(t * 8 + kc) * 32768u +
              ((size_t)rc * 64 + lane) * 16) = pk.v;
  }
}

// Persistent fused LSTM + fc1. 256 blocks x 512 threads (8 waves), 1 block/CU.
// Grouping (r7/r8): 32 groups x 8 members. group g = blockIdx&31 owns batch
// rows [g*16,+16); member m = blockIdx>>5 owns h-cols [m*64,+64).
// Wave wv: nh = wv&3 gate quadrant; kh = wv>>2 K-half. W slice = 192 regs.
// Sync = r8 (proven): subset JIT polling, plain publish + vmcnt drain at
// barrier C, agent flag store, SC1 consumer loads, signal first.
//
// fc1 FUSED (r9 fixed): the h-frags loaded during step t's gates phase are
// h(t-1) — so the fc1 partial computed at step t belongs to a[...][t-1].
// r9's bug: stored it at [t] (off-by-one, absmax 3.58). Fix:
//   - tail at step t (t>0) stores a[...][t-1] (parity t&1 fpart);
//   - post-loop epilogue computes a[...][255] = fc1(h(255)): nh==0 waves
//     poll all flags >= 256, SC1-load their K-half chunks from hswz0
//     (t=255's write buffer), same MFMAs, fpart parity-0, barrier, store.
__global__ __launch_bounds__(512, 2) void lstm_persist(
    const float* __restrict__ Wih, const float* __restrict__ Whh,
    const float* __restrict__ bih, const float* __restrict__ bhh,
    const float* __restrict__ fc1_w, unsigned char* __restrict__ ws)
{
  const int gid = blockIdx.x;
  const int g = gid & 31;                    // group (16 batch rows)
  const int m = gid >> 5;                    // member 0..7 (64 h-cols)
  const int tid = threadIdx.x;
  const int wv = tid >> 6, lane = tid & 63;
  const int nh = wv & 3, kh = wv >> 2;       // gate quadrant, K-half
  const int lq = lane >> 4, ln = lane & 15;  // quad, low nibble

  int* flags_g = (int*)(ws + (size_t)g * 128);   // 8 ints used, zeroed
  unsigned char* xswz  = ws + OFF_XSWZ;
  unsigned char* hswz0 = ws + OFF_HSWZ;
  unsigned char* hswz1 = ws + OFF_HSWZ + 524288;
  float* a_out = (float*)(ws + OFF_HIST);

  // per-lane subset-poll pointers (loop-invariant)
  const int lr3 = lane % 3;
  const int* p01  = flags_g + (lane & 1);        // members 0,1  (kh=0)
  const int* p234 = flags_g + 2 + lr3;           // members 2,3,4 (kh=1)
  const int* p567 = flags_g + 5 + lr3;           // members 5,6,7 (kh=1)

  // ---- W preload: kb = (kh*12+kk)*32 + lq*8 ; Wf[kk][ns] = 192 regs ----
  bf16x8 Wf[12][4];
#pragma unroll
  for (int kk = 0; kk < 12; ++kk) {
    const int kb = (kh * 12 + kk) * 32 + lq * 8;   // never straddles 256
#pragma unroll
    for (int ns = 0; ns < 4; ++ns) {
      const int gcol = nh * 512 + m * 64 + ns * 16 + ln;
      const float* s = (kb < 256) ? (Wih + (size_t)gcol * 256 + kb)
                                  : (Whh + (size_t)gcol * 512 + (kb - 256));
      bf16x8 w;
#pragma unroll
      for (int j = 0; j < 8; ++j) w[j] = (short)f2bf(s[j]);
      Wf[kk][ns] = w;
    }
  }

  // ---- updater cell mapping: thread owns (urow, ujl..ujl+1) ----
  const int urow = tid >> 5;          // 0..15
  const int ujl  = (tid & 31) * 2;    // 0..62 (even)
  float bia2[2][4];
#pragma unroll
  for (int cc = 0; cc < 2; ++cc)
#pragma unroll
    for (int nt = 0; nt < 4; ++nt) {
      int gcol = nt * 512 + m * 64 + ujl + cc;
      bia2[cc][nt] = bih[gcol] + bhh[gcol];
    }

  __shared__ float g_s[8704];                // [kh2][row16][nt4][68] partial preacts
  __shared__ float h_s[1088];                // [row16][68] new h (fp32)
  __shared__ bf16x8 fc1f[2048];              // 32KB fc1 B-frags [chunk16][tile2][lane64]
  __shared__ float fpart[2048];              // 8KB fc1 partials [par2][kh2][tile2][16][16]

  // ---- stage fc1_w into LDS as B-frags (once) ----
#pragma unroll
  for (int i = 0; i < 4; ++i) {
    int s = tid + i * 512;
    int chunk = s >> 7, tile = (s >> 6) & 1, lnn = s & 63;
    int col = tile * 16 + (lnn & 15);
    int kb2 = chunk * 32 + (lnn >> 4) * 8;
    bf16x8 w;
#pragma unroll
    for (int j = 0; j < 8; ++j) w[j] = (short)f2bf(fc1_w[(size_t)col * 512 + kb2 + j]);
    fc1f[chunk * 128 + tile * 64 + lnn] = w;
  }
  __syncthreads();

  float c2[2] = {0.f, 0.f};                  // cell state, 2 cells/thread
  const f32x4 zero4 = {0.f, 0.f, 0.f, 0.f};

#pragma unroll 1
  for (int t = 0; t < 256; ++t) {
    unsigned char* hrd = (t & 1) ? hswz1 : hswz0;
    unsigned char* hwr = (t & 1) ? hswz0 : hswz1;

    f32x4 acc[4] = {zero4, zero4, zero4, zero4};
    f32x4 accf[2] = {zero4, zero4};          // fc1 partial of h(t-1) (nh==0)
    const unsigned char* hbase = hrd + (size_t)g * 1024u + (size_t)lane * 16u;

    if (kh == 0) {
      // ---- x-part (k-chunks 0..7): before the poll ----
#pragma unroll
      for (int kc = 0; kc < 8; ++kc) {
        bf16x8 a = *(const bf16x8*)(xswz + (size_t)(t * 8 + kc) * 32768u +
                                    ((size_t)(g * 64 + lane)) * 16);
#pragma unroll
        for (int ns = 0; ns < 4; ++ns)
          acc[ns] = __builtin_amdgcn_mfma_f32_16x16x32_bf16(a, Wf[kc][ns], acc[ns], 0, 0, 0);
      }
      // ---- JIT poll members 0,1 -> h chunks 0..3 with Wf[8..11] ----
      if (t > 0) { pollw(p01, t); asm volatile("" ::: "memory"); }
      unsigned long long u0[4], u1[4];
#pragma unroll
      for (int p = 0; p < 4; ++p) {
        const unsigned long long* q =
            (const unsigned long long*)(hbase + (size_t)p * 32768u);
        u0[p] = __hip_atomic_load(q + 0, __ATOMIC_RELAXED, __HIP_MEMORY_SCOPE_AGENT);
        u1[p] = __hip_atomic_load(q + 1, __ATOMIC_RELAXED, __HIP_MEMORY_SCOPE_AGENT);
      }
#pragma unroll
      for (int kk = 0; kk < 4; ++kk) {
        union { unsigned long long q[2]; bf16x8 v; } u;
        u.q[0] = u0[kk]; u.q[1] = u1[kk];
#pragma unroll
        for (int ns = 0; ns < 4; ++ns)
          acc[ns] = __builtin_amdgcn_mfma_f32_16x16x32_bf16(u.v, Wf[8 + kk][ns], acc[ns], 0, 0, 0);
        if (nh == 0) {   // fc1 partial: h-chunk kk of h(t-1)
          accf[0] = __builtin_amdgcn_mfma_f32_16x16x32_bf16(u.v, fc1f[kk * 128 + lane], accf[0], 0, 0, 0);
          accf[1] = __builtin_amdgcn_mfma_f32_16x16x32_bf16(u.v, fc1f[kk * 128 + 64 + lane], accf[1], 0, 0, 0);
        }
      }
    } else {
      // ---- JIT poll members 2,3,4 -> preload chunks 4..9 ----
      if (t > 0) { pollw(p234, t); asm volatile("" ::: "memory"); }
      unsigned long long u0[6], u1[6];
#pragma unroll
      for (int p = 0; p < 6; ++p) {
        const unsigned long long* q =
            (const unsigned long long*)(hbase + (size_t)(4 + p) * 32768u);
        u0[p] = __hip_atomic_load(q + 0, __ATOMIC_RELAXED, __HIP_MEMORY_SCOPE_AGENT);
        u1[p] = __hip_atomic_load(q + 1, __ATOMIC_RELAXED, __HIP_MEMORY_SCOPE_AGENT);
      }
      // ---- poll members 5,6,7 while the preload is in flight ----
      if (t > 0) { pollw(p567, t); asm volatile("" ::: "memory"); }
      // ---- rotation: chunks 4..15 with Wf[0..11], depth 6 ----
#pragma unroll
      for (int kk = 0; kk < 12; ++kk) {
        const int slot = kk % 6;
        union { unsigned long long q[2]; bf16x8 v; } u;
        u.q[0] = u0[slot]; u.q[1] = u1[slot];
        if (kk < 6) {
          const unsigned long long* q =
              (const unsigned long long*)(hbase + (size_t)(10 + kk) * 32768u);
          u0[slot] = __hip_atomic_load(q + 0, __ATOMIC_RELAXED, __HIP_MEMORY_SCOPE_AGENT);
          u1[slot] = __hip_atomic_load(q + 1, __ATOMIC_RELAXED, __HIP_MEMORY_SCOPE_AGENT);
        }
#pragma unroll
        for (int ns = 0; ns < 4; ++ns)
          acc[ns] = __builtin_amdgcn_mfma_f32_16x16x32_bf16(u.v, Wf[kk][ns], acc[ns], 0, 0, 0);
        if (nh == 0) {   // fc1 partial: h-chunk 4+kk of h(t-1)
          accf[0] = __builtin_amdgcn_mfma_f32_16x16x32_bf16(u.v, fc1f[(4 + kk) * 128 + lane], accf[0], 0, 0, 0);
          accf[1] = __builtin_amdgcn_mfma_f32_16x16x32_bf16(u.v, fc1f[(4 + kk) * 128 + 64 + lane], accf[1], 0, 0, 0);
        }
      }
    }
    // ---- write partial preacts: g_s[kh][row][nh][col] (C/D: col=ln,row=lq*4+r)
#pragma unroll
    for (int ns = 0; ns < 4; ++ns)
#pragma unroll
      for (int r = 0; r < 4; ++r)
        g_s[((kh * 16 + lq * 4 + r) * 4 + nh) * 68 + ns * 16 + ln] = acc[ns][r];
    // ---- fc1 partials -> fpart[t&1][kh][tile][row][col] (nh==0 waves) ----
    if (nh == 0) {
#pragma unroll
      for (int tile = 0; tile < 2; ++tile)
#pragma unroll
        for (int r = 0; r < 4; ++r)
          fpart[(((t & 1) * 2 + kh) * 2 + tile) * 256 + (lq * 4 + r) * 16 + ln] = accf[tile][r];
    }
    __syncthreads();   // A: partials visible

    // ---- cell update: ALL threads, 2 cells each ----
    {
#pragma unroll
      for (int cc = 0; cc < 2; ++cc) {
        const int jl = ujl + cc;
        float gi = g_s[((0 * 16 + urow) * 4 + 0) * 68 + jl]
                 + g_s[((1 * 16 + urow) * 4 + 0) * 68 + jl] + bia2[cc][0];
        float gf = g_s[((0 * 16 + urow) * 4 + 1) * 68 + jl]
                 + g_s[((1 * 16 + urow) * 4 + 1) * 68 + jl] + bia2[cc][1];
        float gg = g_s[((0 * 16 + urow) * 4 + 2) * 68 + jl]
                 + g_s[((1 * 16 + urow) * 4 + 2) * 68 + jl] + bia2[cc][2];
        float go = g_s[((0 * 16 + urow) * 4 + 3) * 68 + jl]
                 + g_s[((1 * 16 + urow) * 4 + 3) * 68 + jl] + bia2[cc][3];
        float iv = 1.f / (1.f + __expf(-gi));
        float fv = 1.f / (1.f + __expf(-gf));
        float gv = 1.f - 2.f / (__expf(2.f * gg) + 1.f);
        float ov = 1.f / (1.f + __expf(-go));
        float cv = fv * c2[cc] + iv * gv;
        c2[cc] = cv;
        h_s[urow * 68 + jl] = ov * (1.f - 2.f / (__expf(2.f * cv) + 1.f));
      }
    }
    __syncthreads();   // B: h_s ready

    if (tid < 128) {
      // ---- publish member's 2 k-chunks (2KB) in A-frag order: 16B stores ----
      int cc = tid >> 6;                // which of the member's 2 chunks
      int lp = tid & 63;                // frag lane
      union { unsigned short s[8]; uint4 v; } pk;
#pragma unroll
      for (int j = 0; j < 8; ++j)
        pk.s[j] = f2bf(h_s[(lp & 15) * 68 + cc * 32 + (lp >> 4) * 8 + j]);
      *(uint4*)(hwr + (size_t)(2 * m + cc) * 32768u + (size_t)g * 1024u +
                (size_t)lp * 16u) = pk.v;
    }
    __syncthreads();   // C: publish stores drained (vmcnt(0)) -> safe to signal

    // ---- signal FIRST ----
    if (tid == 0)
      __hip_atomic_store(flags_g + m, t + 1, __ATOMIC_RELAXED,
                         __HIP_MEMORY_SCOPE_AGENT);

    // ---- fc1 tail: fpart holds fc1(h(t-1)) -> store a[...][t-1] ----
    // fpart parity (t&1) double-buffer: next write to this half is at t+2's
    // gates phase, behind barrier A(t+1) -> race-free without a barrier here.
    if (m == 0 && t > 0) {
      int row = tid >> 5, col = tid & 31;
      int tile = col >> 4, cl = col & 15;
      float v = fpart[(((t & 1) * 2 + 0) * 2 + tile) * 256 + row * 16 + cl]
              + fpart[(((t & 1) * 2 + 1) * 2 + tile) * 256 + row * 16 + cl];
      a_out[((size_t)(g * 16 + row) * 256 + (t - 1)) * 32 + col] = v;
    }
  }

  // ---- epilogue: a[...][255] = fc1(h(255)) ----
  // h(255) was published into hwr of t=255 = hswz0; signal value = 256.
  if (nh == 0) {
    pollw(flags_g + (lane & 7), 256);          // all 8 members done
    asm volatile("" ::: "memory");
    const unsigned char* hbase = hswz0 + (size_t)g * 1024u + (size_t)lane * 16u;
    f32x4 accf[2] = {zero4, zero4};
    const int c0 = (kh == 0) ? 0 : 4;
    const int cn = (kh == 0) ? 4 : 12;
    for (int kk = 0; kk < cn; ++kk) {
      const int ch = c0 + kk;
      const unsigned long long* q =
          (const unsigned long long*)(hbase + (size_t)ch * 32768u);
      union { unsigned long long qq[2]; bf16x8 v; } u;
      u.qq[0] = __hip_atomic_load(q + 0, __ATOMIC_RELAXED, __HIP_MEMORY_SCOPE_AGENT);
      u.qq[1] = __hip_atomic_load(q + 1, __ATOMIC_RELAXED, __HIP_MEMORY_SCOPE_AGENT);
      accf[0] = __builtin_amdgcn_mfma_f32_16x16x32_bf16(u.v, fc1f[ch * 128 + lane], accf[0], 0, 0, 0);
      accf[1] = __builtin_amdgcn_mfma_f32_16x16x32_bf16(u.v, fc1f[ch * 128 + 64 + lane], accf[1], 0, 0, 0);
    }
#pragma unroll
    for (int tile = 0; tile < 2; ++tile)
#pragma unroll
      for (int r = 0; r < 4; ++r)
        fpart[((0 * 2 + kh) * 2 + tile) * 256 + (lq * 4 + r) * 16 + ln] = accf[tile][r];
  }
  __syncthreads();
  if (m == 0) {
    int row = tid >> 5, col = tid & 31;
    int tile = col >> 4, cl = col & 15;
    float v = fpart[((0 * 2 + 0) * 2 + tile) * 256 + row * 16 + cl]
            + fpart[((0 * 2 + 1) * 2 + tile) * 256 + row * 16 + cl];
    a_out[((size_t)(g * 16 + row) * 256 + 255) * 32 + col] = v;
  }
}

// Epilogue: per-t BN1 + leaky-relu + fc2 + BN2 + relu. One block per t.
__global__ __launch_bounds__(256) void e2_head(
    const float* __restrict__ a_in, const float* __restrict__ fc1_b,
    const float* __restrict__ fc2_w, const float* __restrict__ fc2_b,
    const float* __restrict__ bn1_g, const float* __restrict__ bn1_b,
    const float* __restrict__ bn2_g, const float* __restrict__ bn2_b,
    float* __restrict__ out)
{
  const int t = blockIdx.x, tid = threadIdx.x;
  __shared__ float fb[32], fw[32];
  __shared__ float red[4][2], red2[4][2];
  if (tid < 32) { fb[tid] = fc1_b[tid]; fw[tid] = fc2_w[tid]; }
  __syncthreads();

  float va[2][32];
  float s1 = 0.f, s2 = 0.f;
#pragma unroll
  for (int rr = 0; rr < 2; ++rr) {
    int b = tid * 2 + rr;
    const float* p = a_in + ((size_t)b * 256 + t) * 32;
#pragma unroll
    for (int o = 0; o < 32; ++o) {
      float v = p[o] + fb[o];
      va[rr][o] = v;
      s1 += v; s2 += v * v;
    }
  }
#pragma unroll
  for (int off = 32; off > 0; off >>= 1) {
    s1 += __shfl_down(s1, off);
    s2 += __shfl_down(s2, off);
  }
  if ((tid & 63) == 0) { red[tid >> 6][0] = s1; red[tid >> 6][1] = s2; }
  __syncthreads();
  float tot1 = red[0][0] + red[1][0] + red[2][0] + red[3][0];
  float tot2 = red[0][1] + red[1][1] + red[2][1] + red[3][1];
  float m1 = tot1 * (1.f / 16384.f);
  float v1 = tot2 * (1.f / 16384.f) - m1 * m1;
  float sc1 = bn1_g[t] * rsqrtf(v1 + 1e-5f);
  float sh1 = bn1_b[t];

  float z[2];
  float zs1 = 0.f, zs2 = 0.f;
#pragma unroll
  for (int rr = 0; rr < 2; ++rr) {
    float acc = fc2_b[0];
#pragma unroll
    for (int o = 0; o < 32; ++o) {
      float av = (va[rr][o] - m1) * sc1 + sh1;
      av = (av > 0.f) ? av : 0.1f * av;
      acc += av * fw[o];
    }
    z[rr] = acc; zs1 += acc; zs2 += acc * acc;
  }
#pragma unroll
  for (int off = 32; off > 0; off >>= 1) {
    zs1 += __shfl_down(zs1, off);
    zs2 += __shfl_down(zs2, off);
  }
  if ((tid & 63) == 0) { red2[tid >> 6][0] = zs1; red2[tid >> 6][1] = zs2; }
  __syncthreads();
  float zt1 = red2[0][0] + red2[1][0] + red2[2][0] + red2[3][0];
  float zt2 = red2[0][1] + red2[1][1] + red2[2][1] + red2[3][1];
  float m2 = zt1 * (1.f / 512.f);
  float v2 = zt2 * (1.f / 512.f) - m2 * m2;
  float sc2 = bn2_g[t] * rsqrtf(v2 + 1e-5f);
  float sh2 = bn2_b[t];
#pragma unroll
  for (int rr = 0; rr < 2; ++rr) {
    int b = tid * 2 + rr;
    float res = (z[rr] - m2) * sc2 + sh2;
    out[(size_t)b * 256 + t] = (res > 0.f) ? res : 0.f;
  }
}

extern "C" void kernel_launch(void* const* d_in, const int* in_sizes, int n_in,
                              void* d_out, int out_size, void* d_ws, size_t ws_size,
                              hipStream_t stream) {
  const float* x    = (const float*)d_in[0];
  const float* Wih  = (const float*)d_in[1];
  const float* Whh  = (const float*)d_in[2];
  const float* bih  = (const float*)d_in[3];
  const float* bhh  = (const float*)d_in[4];
  const float* fc1w = (const float*)d_in[5];
  const float* fc1b = (const float*)d_in[6];
  const float* fc2w = (const float*)d_in[7];
  const float* fc2b = (const float*)d_in[8];
  const float* b1g  = (const float*)d_in[9];
  const float* b1b  = (const float*)d_in[10];
  const float* b2g  = (const float*)d_in[11];
  const float* b2b  = (const float*)d_in[12];
  unsigned char* ws = (unsigned char*)d_ws;
  float* out = (float*)d_out;
  float* a_buf = (float*)(ws + OFF_HIST);   // hist region reused for 'a' (fp32)

  zero_k<<<1028, 256, 0, stream>>>((unsigned*)ws, ZERO_WORDS);
  prep_x<<<8192, 256, 0, stream>>>(x, ws);
  lstm_persist<<<256, 512, 0, stream>>>(Wih, Whh, bih, bhh, fc1w, ws);
  e2_head<<<256, 256, 0, stream>>>(a_buf, fc1b, fc2w, fc2b, b1g, b1b, b2g, b2b, out);
}

// Round 12
// 1409.659 us; speedup vs baseline: 1.2184x; 1.2184x over previous
//
#include <hip/hip_runtime.h>

// Problem sizes (fixed)
#define BB 512
#define TT 256
#define II 256
#define HH 512
// K = II + HH = 768 ; 4H = 2048

typedef __attribute__((ext_vector_type(8))) short bf16x8;   // 4 VGPRs (8 bf16)
typedef __attribute__((ext_vector_type(4))) float f32x4;    // 16x16 accumulator

__device__ __forceinline__ unsigned short f2bf(float f) {
  union { float f; unsigned u; } v; v.f = f;
  unsigned r = v.u + 0x7fffu + ((v.u >> 16) & 1u);   // RNE
  return (unsigned short)(r >> 16);
}

// Poll a per-lane flag pointer until *p >= t across the wave (agent scope).
__device__ __forceinline__ void pollw(const int* p, int t) {
  int iter = 0;
  for (;;) {
    int v = __hip_atomic_load(p, __ATOMIC_RELAXED, __HIP_MEMORY_SCOPE_AGENT);
    if (__all(v >= t)) break;
    if (++iter >= (1 << 17)) break;
    __builtin_amdgcn_s_sleep(1);
  }
}

// -------- workspace layout (bytes) --------
// [0,4096)                : per-group member flags (32 groups x 128B; 8 ints used)
// [4096, 4096+2*524288)   : hswz double buffer: [kchunk 16][group 32][lane 64][16B]
// [OFF_XSWZ, +64MB)       : x in A-frag swizzle (bf16): [t][kc 8][rowchunk 32][lane][16B]
// [OFF_HIST, +128MB)      : lstm_out history (bf16, [B*T][H])
#define OFF_CNT   0
#define OFF_HSWZ  4096
#define OFF_XSWZ  1052672ULL
#define OFF_HIST  68161536ULL
#define ZERO_WORDS 263168   // (4096 + 2*524288)/4 == 1028 * 256

// Swizzle x[b][t][k] (fp32) -> xswz[t][kc][rc][lane][8] (bf16), A-frag order.
// Also zeroes the flags + hswz region (first 1028 blocks, one word/thread):
// stream order guarantees completion before lstm_persist launches, so the
// separate zero_k kernel (and its launch overhead) is eliminated.
__global__ __launch_bounds__(256) void prep_x(const float* __restrict__ x,
                                              unsigned char* __restrict__ ws) {
  __shared__ unsigned short xs[16][264];   // 16 rows x 256 k (+8 pad)
  const int t = blockIdx.x >> 5, rc = blockIdx.x & 31;
  const int tid = threadIdx.x;
  if (blockIdx.x < 1028)
    ((unsigned*)ws)[blockIdx.x * 256 + tid] = 0u;   // ZERO_WORDS exactly
  {
    const int r = tid >> 4, seg = tid & 15;
    const float* src = x + ((size_t)(rc * 16 + r) * TT + t) * II + seg * 16;
    const float4* s4 = (const float4*)src;
#pragma unroll
    for (int q = 0; q < 4; ++q) {
      float4 v = s4[q];
      xs[r][seg * 16 + q * 4 + 0] = f2bf(v.x);
      xs[r][seg * 16 + q * 4 + 1] = f2bf(v.y);
      xs[r][seg * 16 + q * 4 + 2] = f2bf(v.z);
      xs[r][seg * 16 + q * 4 + 3] = f2bf(v.w);
    }
  }
  __syncthreads();
  const int lane = tid & 63;
  const int row16 = lane & 15, koff = (lane >> 4) * 8;
#pragma unroll
  for (int kc = tid >> 6; kc < 8; kc += 4) {
    union { unsigned short h[8]; uint4 v; } pk;
#pragma unroll
    for (int j = 0; j < 8; ++j) pk.h[j] = xs[row16][kc * 32 + koff + j];
    *(uint4*)(ws + OFF_XSWZ + (size_t)(t * 8 + kc) * 32768u +
              ((size_t)rc * 64 + lane) * 16) = pk.v;
  }
}

// Persistent fused LSTM. 256 blocks x 512 threads (8 waves), 1 block/CU.
// Grouping: 32 groups x 8 members. group g = blockIdx&31 owns batch rows
// [g*16,+16); member m = blockIdx>>5 owns h-cols [m*64,+64).
// Wave wv: nh = wv&3 gate quadrant; kh = wv>>2 K-half. W slice = 192 regs.
//
// PROVEN BEST (r8, 1205us persist). Ledger of failed deviations:
//   r2 L2-local consumer loads = STALE (buffer_inv is L1-only);
//   r3 x-reg prefetch / r5 asm load ladder = VGPR SPILL (+50-190MB WRITE);
//   r4 sched_barrier pins + undrained barriers = scheduler defeat;
//   r7 LDS-staging the group h (4x MALL cut) = FLAT (not BW-bound);
//   r11 fc1 fused into the h-rotation = +350us (critical-path poison:
//     wave imbalance + perturbed load pipelining; MfmaUtil 14.3->11.9).
// The recurrence loop is latency-fragile: add NOTHING between poll and
// barrier A; never add long-lived registers; never pin the scheduler.
//
// Sync: subset JIT polling — member m's chunks {2m,2m+1} consumable once
// flag[m] >= t. kh=0 polls {0,1} after its x-MFMAs; kh=1 polls {2,3,4},
// issues its 6-chunk preload, polls {5,6,7} while in flight, then rotates.
// Publish: plain 16B stores drained by barrier C (__syncthreads vmcnt(0)),
// agent-scope flag store FIRST, hist stores after (off the signal path).
__global__ __launch_bounds__(512, 2) void lstm_persist(
    const float* __restrict__ Wih, const float* __restrict__ Whh,
    const float* __restrict__ bih, const float* __restrict__ bhh,
    unsigned char* __restrict__ ws)
{
  const int gid = blockIdx.x;
  const int g = gid & 31;                    // group (16 batch rows)
  const int m = gid >> 5;                    // member 0..7 (64 h-cols)
  const int tid = threadIdx.x;
  const int wv = tid >> 6, lane = tid & 63;
  const int nh = wv & 3, kh = wv >> 2;       // gate quadrant, K-half
  const int lq = lane >> 4, ln = lane & 15;  // quad, low nibble

  int* flags_g = (int*)(ws + (size_t)g * 128);   // 8 ints used, zeroed
  unsigned char* xswz  = ws + OFF_XSWZ;
  unsigned char* hswz0 = ws + OFF_HSWZ;
  unsigned char* hswz1 = ws + OFF_HSWZ + 524288;
  unsigned char* hist  = ws + OFF_HIST;

  // per-lane subset-poll pointers (loop-invariant)
  const int lr3 = lane % 3;
  const int* p01  = flags_g + (lane & 1);        // members 0,1  (kh=0)
  const int* p234 = flags_g + 2 + lr3;           // members 2,3,4 (kh=1)
  const int* p567 = flags_g + 5 + lr3;           // members 5,6,7 (kh=1)

  // ---- W preload: kb = (kh*12+kk)*32 + lq*8 ; Wf[kk][ns] = 192 regs ----
  bf16x8 Wf[12][4];
#pragma unroll
  for (int kk = 0; kk < 12; ++kk) {
    const int kb = (kh * 12 + kk) * 32 + lq * 8;   // never straddles 256
#pragma unroll
    for (int ns = 0; ns < 4; ++ns) {
      const int gcol = nh * 512 + m * 64 + ns * 16 + ln;
      const float* s = (kb < 256) ? (Wih + (size_t)gcol * 256 + kb)
                                  : (Whh + (size_t)gcol * 512 + (kb - 256));
      bf16x8 w;
#pragma unroll
      for (int j = 0; j < 8; ++j) w[j] = (short)f2bf(s[j]);
      Wf[kk][ns] = w;
    }
  }

  // ---- updater cell mapping: thread owns (urow, ujl..ujl+1) ----
  const int urow = tid >> 5;          // 0..15
  const int ujl  = (tid & 31) * 2;    // 0..62 (even)
  float bia2[2][4];
#pragma unroll
  for (int cc = 0; cc < 2; ++cc)
#pragma unroll
    for (int nt = 0; nt < 4; ++nt) {
      int gcol = nt * 512 + m * 64 + ujl + cc;
      bia2[cc][nt] = bih[gcol] + bhh[gcol];
    }

  __shared__ float g_s[8704];                // [kh2][row16][nt4][68] partial preacts
  __shared__ float h_s[1088];                // [row16][68] new h (fp32)

  float c2[2] = {0.f, 0.f};                  // cell state, 2 cells/thread
  const f32x4 zero4 = {0.f, 0.f, 0.f, 0.f};

#pragma unroll 1
  for (int t = 0; t < 256; ++t) {
    unsigned char* hrd = (t & 1) ? hswz1 : hswz0;
    unsigned char* hwr = (t & 1) ? hswz0 : hswz1;

    f32x4 acc[4] = {zero4, zero4, zero4, zero4};
    const unsigned char* hbase = hrd + (size_t)g * 1024u + (size_t)lane * 16u;

    if (kh == 0) {
      // ---- x-part (k-chunks 0..7): before the poll ----
#pragma unroll
      for (int kc = 0; kc < 8; ++kc) {
        bf16x8 a = *(const bf16x8*)(xswz + (size_t)(t * 8 + kc) * 32768u +
                                    ((size_t)(g * 64 + lane)) * 16);
#pragma unroll
        for (int ns = 0; ns < 4; ++ns)
          acc[ns] = __builtin_amdgcn_mfma_f32_16x16x32_bf16(a, Wf[kc][ns], acc[ns], 0, 0, 0);
      }
      // ---- JIT poll members 0,1 -> h chunks 0..3 with Wf[8..11] ----
      if (t > 0) { pollw(p01, t); asm volatile("" ::: "memory"); }
      unsigned long long u0[4], u1[4];
#pragma unroll
      for (int p = 0; p < 4; ++p) {
        const unsigned long long* q =
            (const unsigned long long*)(hbase + (size_t)p * 32768u);
        u0[p] = __hip_atomic_load(q + 0, __ATOMIC_RELAXED, __HIP_MEMORY_SCOPE_AGENT);
        u1[p] = __hip_atomic_load(q + 1, __ATOMIC_RELAXED, __HIP_MEMORY_SCOPE_AGENT);
      }
#pragma unroll
      for (int kk = 0; kk < 4; ++kk) {
        union { unsigned long long q[2]; bf16x8 v; } u;
        u.q[0] = u0[kk]; u.q[1] = u1[kk];
#pragma unroll
        for (int ns = 0; ns < 4; ++ns)
          acc[ns] = __builtin_amdgcn_mfma_f32_16x16x32_bf16(u.v, Wf[8 + kk][ns], acc[ns], 0, 0, 0);
      }
    } else {
      // ---- JIT poll members 2,3,4 -> preload chunks 4..9 ----
      if (t > 0) { pollw(p234, t); asm volatile("" ::: "memory"); }
      unsigned long long u0[6], u1[6];
#pragma unroll
      for (int p = 0; p < 6; ++p) {
        const unsigned long long* q =
            (const unsigned long long*)(hbase + (size_t)(4 + p) * 32768u);
        u0[p] = __hip_atomic_load(q + 0, __ATOMIC_RELAXED, __HIP_MEMORY_SCOPE_AGENT);
        u1[p] = __hip_atomic_load(q + 1, __ATOMIC_RELAXED, __HIP_MEMORY_SCOPE_AGENT);
      }
      // ---- poll members 5,6,7 while the preload is in flight ----
      if (t > 0) { pollw(p567, t); asm volatile("" ::: "memory"); }
      // ---- rotation: chunks 4..15 with Wf[0..11], depth 6 ----
#pragma unroll
      for (int kk = 0; kk < 12; ++kk) {
        const int slot = kk % 6;
        union { unsigned long long q[2]; bf16x8 v; } u;
        u.q[0] = u0[slot]; u.q[1] = u1[slot];
        if (kk < 6) {
          const unsigned long long* q =
              (const unsigned long long*)(hbase + (size_t)(10 + kk) * 32768u);
          u0[slot] = __hip_atomic_load(q + 0, __ATOMIC_RELAXED, __HIP_MEMORY_SCOPE_AGENT);
          u1[slot] = __hip_atomic_load(q + 1, __ATOMIC_RELAXED, __HIP_MEMORY_SCOPE_AGENT);
        }
#pragma unroll
        for (int ns = 0; ns < 4; ++ns)
          acc[ns] = __builtin_amdgcn_mfma_f32_16x16x32_bf16(u.v, Wf[kk][ns], acc[ns], 0, 0, 0);
      }
    }
    // ---- write partial preacts: g_s[kh][row][nh][col] (C/D: col=ln,row=lq*4+r)
#pragma unroll
    for (int ns = 0; ns < 4; ++ns)
#pragma unroll
      for (int r = 0; r < 4; ++r)
        g_s[((kh * 16 + lq * 4 + r) * 4 + nh) * 68 + ns * 16 + ln] = acc[ns][r];
    __syncthreads();   // A: partials visible

    // ---- cell update: ALL threads, 2 cells each ----
    {
#pragma unroll
      for (int cc = 0; cc < 2; ++cc) {
        const int jl = ujl + cc;
        float gi = g_s[((0 * 16 + urow) * 4 + 0) * 68 + jl]
                 + g_s[((1 * 16 + urow) * 4 + 0) * 68 + jl] + bia2[cc][0];
        float gf = g_s[((0 * 16 + urow) * 4 + 1) * 68 + jl]
                 + g_s[((1 * 16 + urow) * 4 + 1) * 68 + jl] + bia2[cc][1];
        float gg = g_s[((0 * 16 + urow) * 4 + 2) * 68 + jl]
                 + g_s[((1 * 16 + urow) * 4 + 2) * 68 + jl] + bia2[cc][2];
        float go = g_s[((0 * 16 + urow) * 4 + 3) * 68 + jl]
                 + g_s[((1 * 16 + urow) * 4 + 3) * 68 + jl] + bia2[cc][3];
        float iv = 1.f / (1.f + __expf(-gi));
        float fv = 1.f / (1.f + __expf(-gf));
        float gv = 1.f - 2.f / (__expf(2.f * gg) + 1.f);
        float ov = 1.f / (1.f + __expf(-go));
        float cv = fv * c2[cc] + iv * gv;
        c2[cc] = cv;
        h_s[urow * 68 + jl] = ov * (1.f - 2.f / (__expf(2.f * cv) + 1.f));
      }
    }
    __syncthreads();   // B: h_s ready

    if (tid < 128) {
      // ---- publish member's 2 k-chunks (2KB) in A-frag order: 16B stores ----
      int cc = tid >> 6;                // which of the member's 2 chunks
      int lp = tid & 63;                // frag lane
      union { unsigned short s[8]; uint4 v; } pk;
#pragma unroll
      for (int j = 0; j < 8; ++j)
        pk.s[j] = f2bf(h_s[(lp & 15) * 68 + cc * 32 + (lp >> 4) * 8 + j]);
      *(uint4*)(hwr + (size_t)(2 * m + cc) * 32768u + (size_t)g * 1024u +
                (size_t)lp * 16u) = pk.v;
    }
    __syncthreads();   // C: publish stores drained (vmcnt(0)) -> safe to signal

    // ---- signal FIRST (off the hist-store latency) ----
    if (tid == 0)
      __hip_atomic_store(flags_g + m, t + 1, __ATOMIC_RELAXED,
                         __HIP_MEMORY_SCOPE_AGENT);

    // ---- hist store (plain 16B, via L2): off the signal path ----
    if (tid < 128) {
      int row = tid >> 3, jl0 = (tid & 7) * 8;
      union { unsigned short s[8]; uint4 v; } hq;
#pragma unroll
      for (int j = 0; j < 8; ++j) hq.s[j] = f2bf(h_s[row * 68 + jl0 + j]);
      int b = g * 16 + row;
      *(uint4*)(hist + ((size_t)(b * 256 + t) * 512 + m * 64 + jl0) * 2) = hq.v;
    }
  }
}

// Epilogue 1: a[r][0..32) = lstm_hist[r][:] @ fc1_w^T   (r = b*T + t), fp32 out, no bias.
__global__ __launch_bounds__(256) void e1_fc1(
    const float* __restrict__ fc1_w, const unsigned char* __restrict__ hist,
    float* __restrict__ a_out)
{
  const int tid = threadIdx.x, wv = tid >> 6, lane = tid & 63;
  const int lq = lane >> 4, ln = lane & 15;

  bf16x8 Bf[16][2];
#pragma unroll
  for (int kk = 0; kk < 16; ++kk) {
#pragma unroll
    for (int nt = 0; nt < 2; ++nt) {
      const float* s = fc1_w + (size_t)(nt * 16 + ln) * 512 + kk * 32 + lq * 8;
      bf16x8 w;
#pragma unroll
      for (int j = 0; j < 8; ++j) w[j] = (short)f2bf(s[j]);
      Bf[kk][nt] = w;
    }
  }

  const int rbase = blockIdx.x * 128 + wv * 32;
  const f32x4 zero4 = {0.f, 0.f, 0.f, 0.f};
  f32x4 acc[2][2] = {{zero4, zero4}, {zero4, zero4}};
#pragma unroll
  for (int kk = 0; kk < 16; ++kk) {
    bf16x8 a0 = *(const bf16x8*)(hist + ((size_t)(rbase + ln) * 512 + kk * 32 + lq * 8) * 2);
    bf16x8 a1 = *(const bf16x8*)(hist + ((size_t)(rbase + 16 + ln) * 512 + kk * 32 + lq * 8) * 2);
#pragma unroll
    for (int nt = 0; nt < 2; ++nt) {
      acc[0][nt] = __builtin_amdgcn_mfma_f32_16x16x32_bf16(a0, Bf[kk][nt], acc[0][nt], 0, 0, 0);
      acc[1][nt] = __builtin_amdgcn_mfma_f32_16x16x32_bf16(a1, Bf[kk][nt], acc[1][nt], 0, 0, 0);
    }
  }
#pragma unroll
  for (int mt = 0; mt < 2; ++mt)
#pragma unroll
    for (int nt = 0; nt < 2; ++nt)
#pragma unroll
      for (int r = 0; r < 4; ++r) {
        int row = rbase + mt * 16 + lq * 4 + r;
        a_out[(size_t)row * 32 + nt * 16 + ln] = acc[mt][nt][r];
      }
}

// Epilogue 2: per-t BN1 + leaky-relu + fc2 + BN2 + relu. One block per t.
__global__ __launch_bounds__(256) void e2_head(
    const float* __restrict__ a_in, const float* __restrict__ fc1_b,
    const float* __restrict__ fc2_w, const float* __restrict__ fc2_b,
    const float* __restrict__ bn1_g, const float* __restrict__ bn1_b,
    const float* __restrict__ bn2_g, const float* __restrict__ bn2_b,
    float* __restrict__ out)
{
  const int t = blockIdx.x, tid = threadIdx.x;
  __shared__ float fb[32], fw[32];
  __shared__ float red[4][2], red2[4][2];
  if (tid < 32) { fb[tid] = fc1_b[tid]; fw[tid] = fc2_w[tid]; }
  __syncthreads();

  float va[2][32];
  float s1 = 0.f, s2 = 0.f;
#pragma unroll
  for (int rr = 0; rr < 2; ++rr) {
    int b = tid * 2 + rr;
    const float* p = a_in + ((size_t)b * 256 + t) * 32;
#pragma unroll
    for (int o = 0; o < 32; ++o) {
      float v = p[o] + fb[o];
      va[rr][o] = v;
      s1 += v; s2 += v * v;
    }
  }
#pragma unroll
  for (int off = 32; off > 0; off >>= 1) {
    s1 += __shfl_down(s1, off);
    s2 += __shfl_down(s2, off);
  }
  if ((tid & 63) == 0) { red[tid >> 6][0] = s1; red[tid >> 6][1] = s2; }
  __syncthreads();
  float tot1 = red[0][0] + red[1][0] + red[2][0] + red[3][0];
  float tot2 = red[0][1] + red[1][1] + red[2][1] + red[3][1];
  float m1 = tot1 * (1.f / 16384.f);
  float v1 = tot2 * (1.f / 16384.f) - m1 * m1;
  float sc1 = bn1_g[t] * rsqrtf(v1 + 1e-5f);
  float sh1 = bn1_b[t];

  float z[2];
  float zs1 = 0.f, zs2 = 0.f;
#pragma unroll
  for (int rr = 0; rr < 2; ++rr) {
    float acc = fc2_b[0];
#pragma unroll
    for (int o = 0; o < 32; ++o) {
      float av = (va[rr][o] - m1) * sc1 + sh1;
      av = (av > 0.f) ? av : 0.1f * av;
      acc += av * fw[o];
    }
    z[rr] = acc; zs1 += acc; zs2 += acc * acc;
  }
#pragma unroll
  for (int off = 32; off > 0; off >>= 1) {
    zs1 += __shfl_down(zs1, off);
    zs2 += __shfl_down(zs2, off);
  }
  if ((tid & 63) == 0) { red2[tid >> 6][0] = zs1; red2[tid >> 6][1] = zs2; }
  __syncthreads();
  float zt1 = red2[0][0] + red2[1][0] + red2[2][0] + red2[3][0];
  float zt2 = red2[0][1] + red2[1][1] + red2[2][1] + red2[3][1];
  float m2 = zt1 * (1.f / 512.f);
  float v2 = zt2 * (1.f / 512.f) - m2 * m2;
  float sc2 = bn2_g[t] * rsqrtf(v2 + 1e-5f);
  float sh2 = bn2_b[t];
#pragma unroll
  for (int rr = 0; rr < 2; ++rr) {
    int b = tid * 2 + rr;
    float res = (z[rr] - m2) * sc2 + sh2;
    out[(size_t)b * 256 + t] = (res > 0.f) ? res : 0.f;
  }
}

extern "C" void kernel_launch(void* const* d_in, const int* in_sizes, int n_in,
                              void* d_out, int out_size, void* d_ws, size_t ws_size,
                              hipStream_t stream) {
  const float* x    = (const float*)d_in[0];
  const float* Wih  = (const float*)d_in[1];
  const float* Whh  = (const float*)d_in[2];
  const float* bih  = (const float*)d_in[3];
  const float* bhh  = (const float*)d_in[4];
  const float* fc1w = (const float*)d_in[5];
  const float* fc1b = (const float*)d_in[6];
  const float* fc2w = (const float*)d_in[7];
  const float* fc2b = (const float*)d_in[8];
  const float* b1g  = (const float*)d_in[9];
  const float* b1b  = (const float*)d_in[10];
  const float* b2g  = (const float*)d_in[11];
  const float* b2b  = (const float*)d_in[12];
  unsigned char* ws = (unsigned char*)d_ws;
  float* out = (float*)d_out;
  float* a_buf = (float*)(ws + OFF_XSWZ);   // reuses xswz region after persist

  prep_x<<<8192, 256, 0, stream>>>(x, ws);   // also zeroes flags+hswz (blocks 0..1027)
  lstm_persist<<<256, 512, 0, stream>>>(Wih, Whh, bih, bhh, ws);
  e1_fc1<<<1024, 256, 0, stream>>>(fc1w, ws + OFF_HIST, a_buf);
  e2_head<<<256, 256, 0, stream>>>(a_buf, fc1b, fc2w, fc2b, b1g, b1b, b2g, b2b, out);
}